// Round 4
// baseline (8492.744 us; speedup 1.0000x reference)
//
#include <hip/hip_runtime.h>
#include <stdint.h>
#include <stddef.h>

#define TT   128
#define BB   1024
#define INN  75
#define HH   128
#define KXP  96
#define OUTN 256
#define DECN 9600
#define NBLK 32
#define EPSB 1e-5f

typedef short v8s __attribute__((ext_vector_type(8)));   // 8 bf16 (4 VGPR) MFMA frag
typedef float v4f __attribute__((ext_vector_type(4)));   // 4 fp32 acc frag
typedef unsigned short ush;
typedef unsigned int   u32;
typedef unsigned long long u64;

// ---- static device workspace (fully rewritten every launch) ----
__device__ __align__(256) ush g_xpad[(size_t)TT * BB * KXP];      // x padded to K=96, bf16, [t][b][k]
// h streams declared as u64 so the packed 4-unit atomic stores are provably 8B-aligned
__device__ __align__(256) u64 g_h0s[(size_t)TT * BB * HH / 4];    // h0 stream, per-step-unique [t][b][u]
__device__ __align__(256) u64 g_h1s[(size_t)TT * BB * HH / 4];    // h1 stream, per-step-unique
__device__ __align__(256) ush g_wtih0[NBLK][16][KXP];             // gathered W^T slices per block
__device__ __align__(256) ush g_wthh0[NBLK][16][HH];
__device__ __align__(256) ush g_wtih1[NBLK][16][HH];
__device__ __align__(256) ush g_wthh1[NBLK][16][HH];
__device__ __align__(256) ush g_fcwt[OUTN * HH];                  // fc_w^T [col][k]
__device__ __align__(256) ush g_decwt[(size_t)DECN * OUTN];       // dec_w^T [col][k]
__device__ __align__(256) ush g_emb[BB * OUTN];                   // fc output bf16
__device__ __align__(256) u32 g_ctrS[TT + 2];                     // per-step barrier counters

// ---- helpers ----
__device__ __forceinline__ ush f2bf(float f) {
  u32 u = __float_as_uint(f);
  u32 r = (u + 0x7FFFu + ((u >> 16) & 1u)) >> 16;   // RNE
  return (ush)r;
}
__device__ __forceinline__ float sigf(float x)  { return 1.f / (1.f + __expf(-x)); }
__device__ __forceinline__ float tanhf_(float x){ float e = __expf(2.f * x); return 1.f - 2.f / (e + 1.f); }
__device__ __forceinline__ v8s ld8(const ush* p) { return *reinterpret_cast<const v8s*>(p); }

// ---- prep kernels ----
__global__ void kzero() {
  int idx = threadIdx.x;              // 1 block x 256
  if (idx < TT + 2) g_ctrS[idx] = 0u;
}

__global__ void kpackx(const float* __restrict__ seq) {
  int idx = blockIdx.x * 256 + threadIdx.x;               // < TT*BB*KXP
  int kk = idx % KXP; int rest = idx / KXP;
  int b = rest % BB;  int t = rest / BB;
  float v = (kk < INN) ? seq[((size_t)b * TT + t) * INN + kk] : 0.f;
  g_xpad[idx] = f2bf(v);
}

__global__ void kpackw(const float* __restrict__ Wih0, const float* __restrict__ Whh0,
                       const float* __restrict__ Wih1, const float* __restrict__ Whh1,
                       const float* __restrict__ fcw,  const float* __restrict__ decw) {
  int idx = blockIdx.x * 256 + threadIdx.x;               // grid 10688
  if (idx < 49152) {                                      // wtih0 : 32*16*96
    int kk = idx % KXP; int r = idx / KXP; int nn = r % 16; int nb = r / 16;
    int col = (nn >> 2) * HH + nb * 4 + (nn & 3);
    g_wtih0[nb][nn][kk] = f2bf((kk < INN) ? Wih0[kk * 512 + col] : 0.f);
  } else if (idx < 114688) {                              // wthh0 : 32*16*128
    int j = idx - 49152; int kk = j % HH; int r = j / HH; int nn = r % 16; int nb = r / 16;
    int col = (nn >> 2) * HH + nb * 4 + (nn & 3);
    g_wthh0[nb][nn][kk] = f2bf(Whh0[kk * 512 + col]);
  } else if (idx < 180224) {                              // wtih1
    int j = idx - 114688; int kk = j % HH; int r = j / HH; int nn = r % 16; int nb = r / 16;
    int col = (nn >> 2) * HH + nb * 4 + (nn & 3);
    g_wtih1[nb][nn][kk] = f2bf(Wih1[kk * 512 + col]);
  } else if (idx < 245760) {                              // wthh1
    int j = idx - 180224; int kk = j % HH; int r = j / HH; int nn = r % 16; int nb = r / 16;
    int col = (nn >> 2) * HH + nb * 4 + (nn & 3);
    g_wthh1[nb][nn][kk] = f2bf(Whh1[kk * 512 + col]);
  } else if (idx < 278528) {                              // fc_w^T : 256*128
    int j = idx - 245760; int c = j / HH, k = j % HH;
    g_fcwt[j] = f2bf(fcw[k * OUTN + c]);
  } else {                                                // dec_w^T : 9600*256 (reads coalesced in n)
    int j = idx - 278528; int n = j % DECN, k = j / DECN;
    g_decwt[(size_t)n * OUTN + k] = f2bf(decw[(size_t)k * DECN + n]);
  }
}

// ---- fused persistent recurrent kernel: 32 blocks x 256 thr.
// Block owns units u0..u0+3 (16 gate cols) for BOTH layers; sees the whole batch.
// All BN stats block-local. One grid barrier per step (h broadcast via LLC).
__global__ __launch_bounds__(256, 1) void krec3(
    const float* __restrict__ gih0, const float* __restrict__ bih0,
    const float* __restrict__ ghh0, const float* __restrict__ bhh0,
    const float* __restrict__ b0,   const float* __restrict__ gc0,
    const float* __restrict__ bc0,
    const float* __restrict__ gih1, const float* __restrict__ bih1,
    const float* __restrict__ ghh1, const float* __restrict__ bhh1,
    const float* __restrict__ b1,   const float* __restrict__ gc1,
    const float* __restrict__ bc1) {
  const int tid = threadIdx.x;
  const int w = tid >> 6, l = tid & 63;
  const int lm = l & 15, lq = l >> 4;
  const int nb = blockIdx.x, u0 = nb * 4;
  const int jj = l & 3, rowr = l >> 2;        // pointwise mapping: unit jj, row-in-mtile rowr
  const int R0 = w * 256;                     // wave's row slab
  const int col = (lm >> 2) * HH + u0 + (lm & 3);   // this lane's gate column

  __shared__ float scratch[4][2][16][16];     // [wave][layer][col16][row16] gate exchange (8 KB)
  __shared__ float sstat[4][4][16][2];        // [wave][stream][col16][S,Q] (2 KB)
  __shared__ float scst[4][2][4][2];          // [wave][layer][unit][S,Q]

  const ush* const h0r = reinterpret_cast<const ush*>(g_h0s);
  const ush* const h1r = reinterpret_cast<const ush*>(g_h1s);

  // B-fragments resident for all steps
  v8s bfi0[3], bfh0[4], bfi1[4], bfh1[4];
#pragma unroll
  for (int ks = 0; ks < 3; ++ks) bfi0[ks] = ld8(&g_wtih0[nb][lm][ks * 32 + lq * 8]);
#pragma unroll
  for (int ks = 0; ks < 4; ++ks) {
    bfh0[ks] = ld8(&g_wthh0[nb][lm][ks * 32 + lq * 8]);
    bfi1[ks] = ld8(&g_wtih1[nb][lm][ks * 32 + lq * 8]);
    bfh1[ks] = ld8(&g_wthh1[nb][lm][ks * 32 + lq * 8]);
  }
  // per-col / per-unit params resident
  const float p_gi0 = gih0[col], p_bi0 = bih0[col], p_gh0 = ghh0[col], p_bh0 = bhh0[col], p_b0 = b0[col];
  const float p_gi1 = gih1[col], p_bi1 = bih1[col], p_gh1 = ghh1[col], p_bh1 = bhh1[col], p_b1 = b1[col];
  const float p_gc0 = gc0[u0 + jj], p_bc0 = bc0[u0 + jj];
  const float p_gc1 = gc1[u0 + jj], p_bc1 = bc1[u0 + jj];

  float c0st[16], c1st[16], so0[16], so1[16];
#pragma unroll
  for (int i = 0; i < 16; ++i) { c0st[i] = 0.f; c1st[i] = 0.f; so0[i] = 0.f; so1[i] = 0.f; }

  const v4f vz = {0.f, 0.f, 0.f, 0.f};

  for (int s = 0; s <= TT; ++s) {
    const bool runL0 = (s < TT), runL1 = (s >= 1);

    v4f Pi0[16], Ph0[16], Pi1[16], Ph1[16];
#pragma unroll
    for (int mt = 0; mt < 16; ++mt) { Pi0[mt] = vz; Ph0[mt] = vz; Pi1[mt] = vz; Ph1[mt] = vz; }

    // ---- GEMM phase: 4 streams, block-local stats, accs resident ----
#pragma unroll
    for (int mt = 0; mt < 16; ++mt) {
      const int arow = R0 + mt * 16 + lm;
      if (runL0) {
        const ush* xp = g_xpad + ((size_t)s * BB + arow) * KXP + lq * 8;
#pragma unroll
        for (int ks = 0; ks < 3; ++ks)
          Pi0[mt] = __builtin_amdgcn_mfma_f32_16x16x32_bf16(ld8(xp + ks * 32), bfi0[ks], Pi0[mt], 0, 0, 0);
      }
      if (runL1) {
        const ush* hp = h0r + ((size_t)(s - 1) * BB + arow) * HH + lq * 8;
#pragma unroll
        for (int ks = 0; ks < 4; ++ks) {
          v8s a = ld8(hp + ks * 32);
          if (runL0) Ph0[mt] = __builtin_amdgcn_mfma_f32_16x16x32_bf16(a, bfh0[ks], Ph0[mt], 0, 0, 0);
          Pi1[mt] = __builtin_amdgcn_mfma_f32_16x16x32_bf16(a, bfi1[ks], Pi1[mt], 0, 0, 0);
        }
      }
      if (s >= 2) {
        const ush* hp = h1r + ((size_t)(s - 2) * BB + arow) * HH + lq * 8;
#pragma unroll
        for (int ks = 0; ks < 4; ++ks)
          Ph1[mt] = __builtin_amdgcn_mfma_f32_16x16x32_bf16(ld8(hp + ks * 32), bfh1[ks], Ph1[mt], 0, 0, 0);
      }
    }

    // ---- per-col stats over this wave's 256 rows ----
    float Si0 = 0.f, Qi0 = 0.f, Sh0 = 0.f, Qh0 = 0.f, Si1 = 0.f, Qi1 = 0.f, Sh1 = 0.f, Qh1 = 0.f;
#pragma unroll
    for (int mt = 0; mt < 16; ++mt)
#pragma unroll
      for (int r = 0; r < 4; ++r) {
        float a = Pi0[mt][r]; Si0 += a; Qi0 += a * a;
        float b = Ph0[mt][r]; Sh0 += b; Qh0 += b * b;
        float c = Pi1[mt][r]; Si1 += c; Qi1 += c * c;
        float d = Ph1[mt][r]; Sh1 += d; Qh1 += d * d;
      }
#pragma unroll
    for (int off = 16; off < 64; off <<= 1) {
      Si0 += __shfl_xor(Si0, off); Qi0 += __shfl_xor(Qi0, off);
      Sh0 += __shfl_xor(Sh0, off); Qh0 += __shfl_xor(Qh0, off);
      Si1 += __shfl_xor(Si1, off); Qi1 += __shfl_xor(Qi1, off);
      Sh1 += __shfl_xor(Sh1, off); Qh1 += __shfl_xor(Qh1, off);
    }
    if (l < 16) {
      sstat[w][0][l][0] = Si0; sstat[w][0][l][1] = Qi0;
      sstat[w][1][l][0] = Sh0; sstat[w][1][l][1] = Qh0;
      sstat[w][2][l][0] = Si1; sstat[w][2][l][1] = Qi1;
      sstat[w][3][l][0] = Sh1; sstat[w][3][l][1] = Qh1;
    }
    __syncthreads();
    // coefs for this lane's col (cross-wave sum of partials)
    float S0 = 0.f, Q0 = 0.f, S1 = 0.f, Q1 = 0.f, S2 = 0.f, Q2 = 0.f, S3 = 0.f, Q3 = 0.f;
#pragma unroll
    for (int ww = 0; ww < 4; ++ww) {
      S0 += sstat[ww][0][lm][0]; Q0 += sstat[ww][0][lm][1];
      S1 += sstat[ww][1][lm][0]; Q1 += sstat[ww][1][lm][1];
      S2 += sstat[ww][2][lm][0]; Q2 += sstat[ww][2][lm][1];
      S3 += sstat[ww][3][lm][0]; Q3 += sstat[ww][3][lm][1];
    }
    float mi0 = S0 * (1.f / BB), vi0 = Q0 * (1.f / BB) - mi0 * mi0, ai0 = p_gi0 * rsqrtf(vi0 + EPSB);
    float mh0 = S1 * (1.f / BB), vh0 = Q1 * (1.f / BB) - mh0 * mh0, ah0 = p_gh0 * rsqrtf(vh0 + EPSB);
    float mi1 = S2 * (1.f / BB), vi1 = Q2 * (1.f / BB) - mi1 * mi1, ai1 = p_gi1 * rsqrtf(vi1 + EPSB);
    float mh1 = S3 * (1.f / BB), vh1 = Q3 * (1.f / BB) - mh1 * mh1, ah1 = p_gh1 * rsqrtf(vh1 + EPSB);
    const float D0 = p_bi0 - ai0 * mi0 + p_bh0 - ah0 * mh0 + p_b0;
    const float D1 = p_bi1 - ai1 * mi1 + p_bh1 - ah1 * mh1 + p_b1;

    // ---- gate exchange + pointwise (wave-synchronous, per m-tile) ----
    float cS0 = 0.f, cQ0 = 0.f, cS1 = 0.f, cQ1 = 0.f;
#pragma unroll
    for (int mt = 0; mt < 16; ++mt) {
      v4f g0v, g1v;
#pragma unroll
      for (int r = 0; r < 4; ++r) {
        g0v[r] = ai0 * Pi0[mt][r] + ah0 * Ph0[mt][r] + D0;
        g1v[r] = ai1 * Pi1[mt][r] + ah1 * Ph1[mt][r] + D1;
      }
      __threadfence_block();   // prior m-tile's reads complete before overwrite
      if (runL0) *reinterpret_cast<v4f*>(&scratch[w][0][lm][lq * 4]) = g0v;
      if (runL1) *reinterpret_cast<v4f*>(&scratch[w][1][lm][lq * 4]) = g1v;
      __threadfence_block();   // writes visible wave-wide
      if (runL0) {
        float fv = scratch[w][0][jj][rowr];
        float iv = scratch[w][0][4 + jj][rowr];
        float ov = scratch[w][0][8 + jj][rowr];
        float gv = scratch[w][0][12 + jj][rowr];
        float c1 = sigf(fv) * c0st[mt] + sigf(iv) * tanhf_(gv);
        c0st[mt] = c1; so0[mt] = sigf(ov);
        cS0 += c1; cQ0 += c1 * c1;
      }
      if (runL1) {
        float fv = scratch[w][1][jj][rowr];
        float iv = scratch[w][1][4 + jj][rowr];
        float ov = scratch[w][1][8 + jj][rowr];
        float gv = scratch[w][1][12 + jj][rowr];
        float c1 = sigf(fv) * c1st[mt] + sigf(iv) * tanhf_(gv);
        c1st[mt] = c1; so1[mt] = sigf(ov);
        cS1 += c1; cQ1 += c1 * c1;
      }
    }

    // ---- c-BN stats (block-local): reduce over lanes sharing unit jj ----
#pragma unroll
    for (int off = 4; off < 64; off <<= 1) {
      cS0 += __shfl_xor(cS0, off); cQ0 += __shfl_xor(cQ0, off);
      cS1 += __shfl_xor(cS1, off); cQ1 += __shfl_xor(cQ1, off);
    }
    if (l < 4) {
      scst[w][0][l][0] = cS0; scst[w][0][l][1] = cQ0;
      scst[w][1][l][0] = cS1; scst[w][1][l][1] = cQ1;
    }
    __syncthreads();
    float Sc0 = 0.f, Qc0 = 0.f, Sc1 = 0.f, Qc1 = 0.f;
#pragma unroll
    for (int ww = 0; ww < 4; ++ww) {
      Sc0 += scst[ww][0][jj][0]; Qc0 += scst[ww][0][jj][1];
      Sc1 += scst[ww][1][jj][0]; Qc1 += scst[ww][1][jj][1];
    }
    float mc0 = Sc0 * (1.f / BB), vc0 = Qc0 * (1.f / BB) - mc0 * mc0;
    float ac0 = p_gc0 * rsqrtf(vc0 + EPSB), dc0 = p_bc0 - ac0 * mc0;
    float mc1 = Sc1 * (1.f / BB), vc1 = Qc1 * (1.f / BB) - mc1 * mc1;
    float ac1 = p_gc1 * rsqrtf(vc1 + EPSB), dc1 = p_bc1 - ac1 * mc1;

    // ---- h outputs: pack 4 units/row, write-through to LLC (u64-typed -> provably aligned) ----
    if (runL0) {
#pragma unroll
      for (int mt = 0; mt < 16; ++mt) {
        float h = so0[mt] * tanhf_(ac0 * c0st[mt] + dc0);
        u32 v = (u32)f2bf(h);
        u32 vp = __shfl_xor(v, 1);
        u32 p2 = v | (vp << 16);                 // valid on even-jj lanes
        u32 q = __shfl_xor(p2, 2);
        if ((l & 3) == 0) {
          int row = R0 + mt * 16 + rowr;
          u64 pk = (u64)p2 | ((u64)q << 32);
          __hip_atomic_store(&g_h0s[((size_t)s * BB + row) * (HH / 4) + nb],
                             pk, __ATOMIC_RELAXED, __HIP_MEMORY_SCOPE_AGENT);
        }
      }
    }
    if (runL1) {
#pragma unroll
      for (int mt = 0; mt < 16; ++mt) {
        float h = so1[mt] * tanhf_(ac1 * c1st[mt] + dc1);
        u32 v = (u32)f2bf(h);
        u32 vp = __shfl_xor(v, 1);
        u32 p2 = v | (vp << 16);
        u32 q = __shfl_xor(p2, 2);
        if ((l & 3) == 0) {
          int row = R0 + mt * 16 + rowr;
          u64 pk = (u64)p2 | ((u64)q << 32);
          __hip_atomic_store(&g_h1s[((size_t)(s - 1) * BB + row) * (HH / 4) + nb],
                             pk, __ATOMIC_RELAXED, __HIP_MEMORY_SCOPE_AGENT);
        }
      }
    }

    // ---- single grid barrier per step ----
    if (s < TT) {
      __builtin_amdgcn_s_waitcnt(0x0f70);   // vmcnt(0): h stores acked at coherence point
      __syncthreads();
      if (tid == 0) {
        __hip_atomic_fetch_add(&g_ctrS[s], 1u, __ATOMIC_RELEASE, __HIP_MEMORY_SCOPE_AGENT);
        while (__hip_atomic_load(&g_ctrS[s], __ATOMIC_RELAXED, __HIP_MEMORY_SCOPE_AGENT) < NBLK)
          __builtin_amdgcn_s_sleep(1);
      }
      __syncthreads();
    }
  }
}

// ---- epilogue: emb = h_last @ fc_w + fc_b (bf16 out) ----
__global__ __launch_bounds__(256) void kfc(const float* __restrict__ fcb) {
  const int tid = threadIdx.x, w = tid >> 6, l = tid & 63;
  const int lm = l & 15, lq = l >> 4;
  const int col = blockIdx.x * 16 + lm;   // grid 16
  const ush* hsrc = reinterpret_cast<const ush*>(g_h1s) + (size_t)(TT - 1) * BB * HH;
  v8s bf[4];
#pragma unroll
  for (int ks = 0; ks < 4; ++ks) bf[ks] = ld8(&g_fcwt[col * HH + ks * 32 + lq * 8]);
  const float bias = fcb[col];
  const v4f vz = {0.f, 0.f, 0.f, 0.f};
#pragma unroll
  for (int mt = 0; mt < 16; ++mt) {
    const int rowa = w * 256 + mt * 16 + lm;
    const ush* ap = hsrc + (size_t)rowa * HH + lq * 8;
    v4f acc = vz;
#pragma unroll
    for (int ks = 0; ks < 4; ++ks)
      acc = __builtin_amdgcn_mfma_f32_16x16x32_bf16(ld8(ap + ks * 32), bf[ks], acc, 0, 0, 0);
#pragma unroll
    for (int r = 0; r < 4; ++r) {
      int row = w * 256 + mt * 16 + lq * 4 + r;
      g_emb[row * OUTN + col] = f2bf(acc[r] + bias);
    }
  }
}

// ---- epilogue: out = emb @ dec_w + dec_b (fp32 out) ----
__global__ __launch_bounds__(256) void kdec(const float* __restrict__ decb, float* __restrict__ out) {
  const int tid = threadIdx.x, w = tid >> 6, l = tid & 63;
  const int lm = l & 15, lq = l >> 4;
  const int col = blockIdx.x * 16 + lm;   // grid 600
  v8s bf[8];
#pragma unroll
  for (int ks = 0; ks < 8; ++ks) bf[ks] = ld8(&g_decwt[(size_t)col * OUTN + ks * 32 + lq * 8]);
  const float bias = decb[col];
  const v4f vz = {0.f, 0.f, 0.f, 0.f};
#pragma unroll
  for (int mt = 0; mt < 16; ++mt) {
    const int rowa = w * 256 + mt * 16 + lm;
    const ush* ap = g_emb + (size_t)rowa * OUTN + lq * 8;
    v4f acc = vz;
#pragma unroll
    for (int ks = 0; ks < 8; ++ks)
      acc = __builtin_amdgcn_mfma_f32_16x16x32_bf16(ld8(ap + ks * 32), bf[ks], acc, 0, 0, 0);
#pragma unroll
    for (int r = 0; r < 4; ++r) {
      int row = w * 256 + mt * 16 + lq * 4 + r;
      out[(size_t)row * DECN + col] = acc[r] + bias;
    }
  }
}

extern "C" void kernel_launch(void* const* d_in, const int* in_sizes, int n_in,
                              void* d_out, int out_size, void* d_ws, size_t ws_size,
                              hipStream_t stream) {
  const float* seq  = (const float*)d_in[0];
  const float* Wih0 = (const float*)d_in[1];
  const float* Whh0 = (const float*)d_in[2];
  const float* b0   = (const float*)d_in[3];
  const float* gih0 = (const float*)d_in[4];
  const float* bih0 = (const float*)d_in[5];
  const float* ghh0 = (const float*)d_in[6];
  const float* bhh0 = (const float*)d_in[7];
  const float* gc0  = (const float*)d_in[8];
  const float* bc0  = (const float*)d_in[9];
  const float* Wih1 = (const float*)d_in[10];
  const float* Whh1 = (const float*)d_in[11];
  const float* b1   = (const float*)d_in[12];
  const float* gih1 = (const float*)d_in[13];
  const float* bih1 = (const float*)d_in[14];
  const float* ghh1 = (const float*)d_in[15];
  const float* bhh1 = (const float*)d_in[16];
  const float* gc1  = (const float*)d_in[17];
  const float* bc1  = (const float*)d_in[18];
  const float* fcw  = (const float*)d_in[19];
  const float* fcb  = (const float*)d_in[20];
  const float* decw = (const float*)d_in[21];
  const float* decb = (const float*)d_in[22];
  float* out = (float*)d_out;
  (void)in_sizes; (void)n_in; (void)out_size; (void)d_ws; (void)ws_size;

  kzero<<<dim3(1), dim3(256), 0, stream>>>();
  kpackx<<<dim3((TT * BB * KXP) / 256), dim3(256), 0, stream>>>(seq);
  kpackw<<<dim3(10688), dim3(256), 0, stream>>>(Wih0, Whh0, Wih1, Whh1, fcw, decw);
  krec3<<<dim3(NBLK), dim3(256), 0, stream>>>(gih0, bih0, ghh0, bhh0, b0, gc0, bc0,
                                              gih1, bih1, ghh1, bhh1, b1, gc1, bc1);
  kfc<<<dim3(16), dim3(256), 0, stream>>>(fcb);
  kdec<<<dim3(600), dim3(256), 0, stream>>>(decb, out);
}

// Round 5
// 5647.656 us; speedup vs baseline: 1.5038x; 1.5038x over previous
//
#include <hip/hip_runtime.h>
#include <stdint.h>
#include <stddef.h>

#define TT   128
#define BB   1024
#define INN  75
#define HH   128
#define KXP  96
#define OUTN 256
#define DECN 9600
#define NBLK 32
#define NTHR 512
#define ROWS 32
#define EPSB 1e-5f

typedef short v8s __attribute__((ext_vector_type(8)));   // 8 bf16 (4 VGPR) MFMA frag
typedef float v4f __attribute__((ext_vector_type(4)));   // 4 fp32 acc frag
typedef unsigned short ush;
typedef unsigned int   u32;
typedef unsigned long long u64;

// ---- static device workspace (fully rewritten every launch) ----
__device__ __align__(256) ush g_xpad[(size_t)TT * BB * KXP];    // x padded to K=96, bf16, [t][b][k]
__device__ __align__(256) ush g_G1c[(size_t)TT * 512 * BB];     // BN(x@Wih0)+b0, [t][col][row] bf16
__device__ __align__(256) ush g_wtih0[512 * KXP];               // W^T [col][k] bf16
__device__ __align__(256) ush g_wthh0[512 * HH];
__device__ __align__(256) ush g_wtih1[512 * HH];
__device__ __align__(256) ush g_wthh1[512 * HH];
__device__ __align__(256) ush g_fcwt[OUTN * HH];                // fc_w^T [col][k]
__device__ __align__(256) ush g_decwt[(size_t)DECN * OUTN];     // dec_w^T [col][k]
__device__ __align__(256) ush g_hlast[BB * HH];                 // h1(T-1) [row][u] bf16
__device__ __align__(256) ush g_emb[BB * OUTN];                 // fc output bf16
// stats per parity: [0,3072): gates (stream st*1024 + col*2 {S,Q}); [3072,3584): c ({layer*256 + u*2})
__device__ __align__(256) float g_stats[2][3584];
__device__ __align__(256) u32 g_ctrS[2 * (TT + 1) + 4];         // per-step barrier counters

// ---- helpers ----
__device__ __forceinline__ ush f2bf(float f) {
  u32 u = __float_as_uint(f);
  u32 r = (u + 0x7FFFu + ((u >> 16) & 1u)) >> 16;   // RNE
  return (ush)r;
}
__device__ __forceinline__ float bf2f(ush u) { return __uint_as_float(((u32)u) << 16); }
__device__ __forceinline__ float sigf(float x)  { return 1.f / (1.f + __expf(-x)); }
__device__ __forceinline__ float tanhf_(float x){ float e = __expf(2.f * x); return 1.f - 2.f / (e + 1.f); }
__device__ __forceinline__ v8s ld8(const ush* p) { return *reinterpret_cast<const v8s*>(p); }
__device__ __forceinline__ void sadd(float* p, float v) {
  __hip_atomic_fetch_add(p, v, __ATOMIC_RELAXED, __HIP_MEMORY_SCOPE_AGENT);
}
__device__ __forceinline__ void szero(float* p) {
  __hip_atomic_store(p, 0.f, __ATOMIC_RELAXED, __HIP_MEMORY_SCOPE_AGENT);
}
__device__ __forceinline__ void ld_sq(const float* p, float& S, float& Q) {
  u64 v = __hip_atomic_load(reinterpret_cast<const u64*>(p), __ATOMIC_RELAXED, __HIP_MEMORY_SCOPE_AGENT);
  S = __uint_as_float((u32)v); Q = __uint_as_float((u32)(v >> 32));
}

// ---- prep kernels ----
__global__ void kzero() {
  int idx = blockIdx.x * 256 + threadIdx.x;   // grid 32
  if (idx < 2 * 3584) ((float*)g_stats)[idx] = 0.f;
  if (idx < 2 * (TT + 1) + 4) g_ctrS[idx] = 0u;
}

__global__ void kpackx(const float* __restrict__ seq) {
  int idx = blockIdx.x * 256 + threadIdx.x;   // < TT*BB*KXP
  int kk = idx % KXP; int rest = idx / KXP;
  int b = rest % BB;  int t = rest / BB;
  float v = (kk < INN) ? seq[((size_t)b * TT + t) * INN + kk] : 0.f;
  g_xpad[idx] = f2bf(v);
}

__global__ void kpackw(const float* __restrict__ Wih0, const float* __restrict__ Whh0,
                       const float* __restrict__ Wih1, const float* __restrict__ Whh1,
                       const float* __restrict__ fcw,  const float* __restrict__ decw) {
  int idx = blockIdx.x * 256 + threadIdx.x;   // grid 10688
  if (idx < 49152) {                          // wtih0: [c][96]
    int c = idx / KXP, k = idx % KXP;
    g_wtih0[idx] = f2bf((k < INN) ? Wih0[k * 512 + c] : 0.f);
  } else if (idx < 114688) {
    int j = idx - 49152; int c = j / HH, k = j % HH;
    g_wthh0[j] = f2bf(Whh0[k * 512 + c]);
  } else if (idx < 180224) {
    int j = idx - 114688; int c = j / HH, k = j % HH;
    g_wtih1[j] = f2bf(Wih1[k * 512 + c]);
  } else if (idx < 245760) {
    int j = idx - 180224; int c = j / HH, k = j % HH;
    g_wthh1[j] = f2bf(Whh1[k * 512 + c]);
  } else if (idx < 278528) {                  // fcwt [c][128]
    int j = idx - 245760; int c = j / HH, k = j % HH;
    g_fcwt[j] = f2bf(fcw[k * OUTN + c]);
  } else {                                    // decwt [c][256], coalesced reads
    int j = idx - 278528; int n = j % DECN, k = j / DECN;
    g_decwt[(size_t)n * OUTN + k] = f2bf(decw[(size_t)k * DECN + n]);
  }
}

// G1c[t][col][row] = BN_ih0(x_t @ Wih0)[col] + b0[col]
__global__ __launch_bounds__(256) void kprep(const float* __restrict__ gih0,
                                             const float* __restrict__ bih0,
                                             const float* __restrict__ b0) {
  const int t = blockIdx.x >> 5, ct = blockIdx.x & 31;    // grid 4096
  const int tid = threadIdx.x, w = tid >> 6, l = tid & 63;
  const int lm = l & 15, lq = l >> 4;
  __shared__ float sred[4][16][2];

  v8s bfi[3];
#pragma unroll
  for (int ks = 0; ks < 3; ++ks) bfi[ks] = ld8(&g_wtih0[(ct * 16 + lm) * KXP + ks * 32 + lq * 8]);

  const v4f vz = {0.f, 0.f, 0.f, 0.f};
  v4f acc[16];
#pragma unroll
  for (int mt = 0; mt < 16; ++mt) acc[mt] = vz;
#pragma unroll
  for (int mt = 0; mt < 16; ++mt) {
    const ush* ap = g_xpad + ((size_t)t * BB + w * 256 + mt * 16 + lm) * KXP + lq * 8;
#pragma unroll
    for (int ks = 0; ks < 3; ++ks)
      acc[mt] = __builtin_amdgcn_mfma_f32_16x16x32_bf16(ld8(ap + ks * 32), bfi[ks], acc[mt], 0, 0, 0);
  }
  float S = 0.f, Q = 0.f;
#pragma unroll
  for (int mt = 0; mt < 16; ++mt)
#pragma unroll
    for (int r = 0; r < 4; ++r) { float a = acc[mt][r]; S += a; Q += a * a; }
  S += __shfl_xor(S, 16); Q += __shfl_xor(Q, 16);
  S += __shfl_xor(S, 32); Q += __shfl_xor(Q, 32);
  if (l < 16) { sred[w][l][0] = S; sred[w][l][1] = Q; }
  __syncthreads();
  float Sa = 0.f, Qa = 0.f;
#pragma unroll
  for (int ww = 0; ww < 4; ++ww) { Sa += sred[ww][lm][0]; Qa += sred[ww][lm][1]; }
  const int col = ct * 16 + lm;
  float m_ = Sa * (1.f / BB), v_ = Qa * (1.f / BB) - m_ * m_;
  float a_ = gih0[col] * rsqrtf(v_ + EPSB);
  float d_ = bih0[col] - a_ * m_ + b0[col];
  ush* dst = g_G1c + ((size_t)(t * 512 + col)) * BB;
#pragma unroll
  for (int mt = 0; mt < 16; ++mt) {
    u32 p0 = (u32)f2bf(a_ * acc[mt][0] + d_) | ((u32)f2bf(a_ * acc[mt][1] + d_) << 16);
    u32 p1 = (u32)f2bf(a_ * acc[mt][2] + d_) | ((u32)f2bf(a_ * acc[mt][3] + d_) << 16);
    uint2 pk; pk.x = p0; pk.y = p1;
    *reinterpret_cast<uint2*>(dst + w * 256 + mt * 16 + lq * 4) = pk;
  }
}

// ---- fused persistent recurrent kernel: 32 blocks x 512 thr (8 waves).
// Block owns 32 batch rows for BOTH layers; h tiles live in LDS.
// Wave wv owns units wv*16+lm -> its 4 gate cols land in the SAME lane (in-register pointwise).
// Stats: recompute-GEMM two-pass, atomicAdd partials (1 add/col/block), 2 grid barriers/step.
__global__ __launch_bounds__(NTHR, 1) void krec5(
    const float* __restrict__ ghh0, const float* __restrict__ bhh0,
    const float* __restrict__ gc0,  const float* __restrict__ bc0,
    const float* __restrict__ gih1, const float* __restrict__ bih1,
    const float* __restrict__ ghh1, const float* __restrict__ bhh1,
    const float* __restrict__ b1,   const float* __restrict__ gc1,
    const float* __restrict__ bc1) {
  const int tid = threadIdx.x;
  const int wv = tid >> 6, l = tid & 63;
  const int lm = l & 15, lq = l >> 4;
  const int nb = blockIdx.x, row0 = nb * ROWS;
  const int u = wv * 16 + lm;                 // this lane's hidden unit

  __shared__ ush h0t[ROWS][136];              // +8 pad: b128-aligned rows, spread banks
  __shared__ ush h1t[ROWS][136];
  for (int i = tid; i < ROWS * 136; i += NTHR) { (&h0t[0][0])[i] = 0; (&h1t[0][0])[i] = 0; }
  __syncthreads();

  // resident per-lane params for the lane's 4 gate cols (col = gi*128 + u)
  float w_gh0[4], w_bh0[4], w_gi1[4], w_bi1[4], w_gh1[4], w_bh1[4], w_b1[4];
#pragma unroll
  for (int gi = 0; gi < 4; ++gi) {
    int col = gi * 128 + u;
    w_gh0[gi] = ghh0[col]; w_bh0[gi] = bhh0[col];
    w_gi1[gi] = gih1[col]; w_bi1[gi] = bih1[col];
    w_gh1[gi] = ghh1[col]; w_bh1[gi] = bhh1[col];
    w_b1[gi]  = b1[col];
  }
  const float p_gc0 = gc0[u], p_bc0 = bc0[u];
  const float p_gc1 = gc1[u], p_bc1 = bc1[u];

  float c0st[2][4], c1st[2][4], so0[2][4], so1[2][4];
#pragma unroll
  for (int mt = 0; mt < 2; ++mt)
#pragma unroll
    for (int r = 0; r < 4; ++r) { c0st[mt][r] = 0.f; c1st[mt][r] = 0.f; so0[mt][r] = 0.f; so1[mt][r] = 0.f; }

  const v4f vz = {0.f, 0.f, 0.f, 0.f};

  for (int s = 0; s <= TT; ++s) {
    const int p = s & 1;
    const bool runL0 = (s < TT), runL1 = (s >= 1);
    float* stp = &g_stats[p][0];

    // early: G1c loads for this lane's 4 gate cols x 2 m-tiles
    uint2 g1ld[4][2];
    if (runL0) {
#pragma unroll
      for (int gi = 0; gi < 4; ++gi)
#pragma unroll
        for (int mt = 0; mt < 2; ++mt)
          g1ld[gi][mt] = *reinterpret_cast<const uint2*>(
              g_G1c + ((size_t)(s * 512 + gi * 128 + u)) * BB + row0 + mt * 16 + lq * 4);
    }

    // h0 A-frags hoisted for the whole step (tiles stable until phase C)
    v8s a0f[2][4];
#pragma unroll
    for (int mt = 0; mt < 2; ++mt)
#pragma unroll
      for (int ks = 0; ks < 4; ++ks)
        a0f[mt][ks] = ld8(&h0t[mt * 16 + lm][ks * 32 + lq * 8]);

    // ================= PASS 1: GEMM -> S,Q only =================
    float SQ[3][4][2];
#pragma unroll
    for (int st = 0; st < 3; ++st)
#pragma unroll
      for (int gi = 0; gi < 4; ++gi) { SQ[st][gi][0] = 0.f; SQ[st][gi][1] = 0.f; }
#pragma unroll
    for (int gi = 0; gi < 4; ++gi) {
      const int col = gi * 128 + u;
      const ush* w0 = g_wthh0 + col * HH + lq * 8;
      const ush* w1 = g_wtih1 + col * HH + lq * 8;
      const ush* w2 = g_wthh1 + col * HH + lq * 8;
      v4f P0[2] = {vz, vz}, P1[2] = {vz, vz}, P2[2] = {vz, vz};
#pragma unroll
      for (int ks = 0; ks < 4; ++ks) {
        v8s b0f = ld8(w0 + ks * 32), b1f = ld8(w1 + ks * 32), b2f = ld8(w2 + ks * 32);
#pragma unroll
        for (int mt = 0; mt < 2; ++mt) {
          v8s a1 = ld8(&h1t[mt * 16 + lm][ks * 32 + lq * 8]);
          P0[mt] = __builtin_amdgcn_mfma_f32_16x16x32_bf16(a0f[mt][ks], b0f, P0[mt], 0, 0, 0);
          P1[mt] = __builtin_amdgcn_mfma_f32_16x16x32_bf16(a0f[mt][ks], b1f, P1[mt], 0, 0, 0);
          P2[mt] = __builtin_amdgcn_mfma_f32_16x16x32_bf16(a1,         b2f, P2[mt], 0, 0, 0);
        }
      }
#pragma unroll
      for (int mt = 0; mt < 2; ++mt)
#pragma unroll
        for (int r = 0; r < 4; ++r) {
          float a = P0[mt][r]; SQ[0][gi][0] += a; SQ[0][gi][1] += a * a;
          float b = P1[mt][r]; SQ[1][gi][0] += b; SQ[1][gi][1] += b * b;
          float c = P2[mt][r]; SQ[2][gi][0] += c; SQ[2][gi][1] += c * c;
        }
    }
#pragma unroll
    for (int st = 0; st < 3; ++st)
#pragma unroll
      for (int gi = 0; gi < 4; ++gi) {
        float S = SQ[st][gi][0], Q = SQ[st][gi][1];
        S += __shfl_xor(S, 16); Q += __shfl_xor(Q, 16);
        S += __shfl_xor(S, 32); Q += __shfl_xor(Q, 32);
        if (lq == 0) {
          int col = gi * 128 + u;
          sadd(&stp[st * 1024 + col * 2], S);
          sadd(&stp[st * 1024 + col * 2 + 1], Q);
        }
      }

    // ---- grid barrier A ----
    __builtin_amdgcn_s_waitcnt(0x0f70);   // vmcnt(0)
    __syncthreads();
    if (tid == 0) {
      __hip_atomic_fetch_add(&g_ctrS[2 * s], 1u, __ATOMIC_RELEASE, __HIP_MEMORY_SCOPE_AGENT);
      while (__hip_atomic_load(&g_ctrS[2 * s], __ATOMIC_RELAXED, __HIP_MEMORY_SCOPE_AGENT) < NBLK)
        __builtin_amdgcn_s_sleep(1);
    }
    __syncthreads();

    // ---- coefs (redundant per consumer lane; reads hit LLC) ----
    float A0[4], Dh0[4], Ai1[4], Ah1[4], D1[4];
#pragma unroll
    for (int gi = 0; gi < 4; ++gi) {
      const int col = gi * 128 + u;
      float S, Q;
      ld_sq(&stp[col * 2], S, Q);
      float m_ = S * (1.f / BB), v_ = Q * (1.f / BB) - m_ * m_;
      A0[gi] = w_gh0[gi] * rsqrtf(v_ + EPSB);
      Dh0[gi] = w_bh0[gi] - A0[gi] * m_;
      ld_sq(&stp[1024 + col * 2], S, Q);
      m_ = S * (1.f / BB); v_ = Q * (1.f / BB) - m_ * m_;
      Ai1[gi] = w_gi1[gi] * rsqrtf(v_ + EPSB);
      float d1 = w_bi1[gi] - Ai1[gi] * m_ + w_b1[gi];
      ld_sq(&stp[2048 + col * 2], S, Q);
      m_ = S * (1.f / BB); v_ = Q * (1.f / BB) - m_ * m_;
      Ah1[gi] = w_gh1[gi] * rsqrtf(v_ + EPSB);
      D1[gi] = d1 + w_bh1[gi] - Ah1[gi] * m_;
    }

    // ================= PASS 2: recompute GEMM, form gates in-register =================
    float g0a[4][2][4], g1a[4][2][4];
#pragma unroll
    for (int gi = 0; gi < 4; ++gi) {
      const int col = gi * 128 + u;
      const ush* w0 = g_wthh0 + col * HH + lq * 8;
      const ush* w1 = g_wtih1 + col * HH + lq * 8;
      const ush* w2 = g_wthh1 + col * HH + lq * 8;
      v4f P0[2] = {vz, vz}, P1[2] = {vz, vz}, P2[2] = {vz, vz};
#pragma unroll
      for (int ks = 0; ks < 4; ++ks) {
        v8s b0f = ld8(w0 + ks * 32), b1f = ld8(w1 + ks * 32), b2f = ld8(w2 + ks * 32);
#pragma unroll
        for (int mt = 0; mt < 2; ++mt) {
          v8s a1 = ld8(&h1t[mt * 16 + lm][ks * 32 + lq * 8]);
          P0[mt] = __builtin_amdgcn_mfma_f32_16x16x32_bf16(a0f[mt][ks], b0f, P0[mt], 0, 0, 0);
          P1[mt] = __builtin_amdgcn_mfma_f32_16x16x32_bf16(a0f[mt][ks], b1f, P1[mt], 0, 0, 0);
          P2[mt] = __builtin_amdgcn_mfma_f32_16x16x32_bf16(a1,         b2f, P2[mt], 0, 0, 0);
        }
      }
#pragma unroll
      for (int mt = 0; mt < 2; ++mt) {
        float bv[4] = {0.f, 0.f, 0.f, 0.f};
        if (runL0) {
          uint2 pk = g1ld[gi][mt];
          bv[0] = bf2f((ush)pk.x); bv[1] = bf2f((ush)(pk.x >> 16));
          bv[2] = bf2f((ush)pk.y); bv[3] = bf2f((ush)(pk.y >> 16));
        }
#pragma unroll
        for (int r = 0; r < 4; ++r) {
          g0a[gi][mt][r] = bv[r] + A0[gi] * P0[mt][r] + Dh0[gi];
          g1a[gi][mt][r] = Ai1[gi] * P1[mt][r] + Ah1[gi] * P2[mt][r] + D1[gi];
        }
      }
    }

    // ---- pointwise, fully in-register (gate order f,i,o,g = gi 0..3) ----
    float cS0 = 0.f, cQ0 = 0.f, cS1 = 0.f, cQ1 = 0.f;
    if (runL0) {
#pragma unroll
      for (int mt = 0; mt < 2; ++mt)
#pragma unroll
        for (int r = 0; r < 4; ++r) {
          float c1 = sigf(g0a[0][mt][r]) * c0st[mt][r] + sigf(g0a[1][mt][r]) * tanhf_(g0a[3][mt][r]);
          c0st[mt][r] = c1; so0[mt][r] = sigf(g0a[2][mt][r]);
          cS0 += c1; cQ0 += c1 * c1;
        }
    }
    if (runL1) {
#pragma unroll
      for (int mt = 0; mt < 2; ++mt)
#pragma unroll
        for (int r = 0; r < 4; ++r) {
          float c1 = sigf(g1a[0][mt][r]) * c1st[mt][r] + sigf(g1a[1][mt][r]) * tanhf_(g1a[3][mt][r]);
          c1st[mt][r] = c1; so1[mt][r] = sigf(g1a[2][mt][r]);
          cS1 += c1; cQ1 += c1 * c1;
        }
    }
    // c-stat partials: reduce over row-groups (lanes sharing lm)
    cS0 += __shfl_xor(cS0, 16); cQ0 += __shfl_xor(cQ0, 16);
    cS0 += __shfl_xor(cS0, 32); cQ0 += __shfl_xor(cQ0, 32);
    cS1 += __shfl_xor(cS1, 16); cQ1 += __shfl_xor(cQ1, 16);
    cS1 += __shfl_xor(cS1, 32); cQ1 += __shfl_xor(cQ1, 32);
    if (lq == 0) {
      sadd(&stp[3072 + u * 2], cS0);       sadd(&stp[3072 + u * 2 + 1], cQ0);
      sadd(&stp[3072 + 256 + u * 2], cS1); sadd(&stp[3072 + 256 + u * 2 + 1], cQ1);
    }

    // ---- grid barrier B ----
    __builtin_amdgcn_s_waitcnt(0x0f70);
    __syncthreads();
    if (tid == 0) {
      __hip_atomic_fetch_add(&g_ctrS[2 * s + 1], 1u, __ATOMIC_RELEASE, __HIP_MEMORY_SCOPE_AGENT);
      while (__hip_atomic_load(&g_ctrS[2 * s + 1], __ATOMIC_RELAXED, __HIP_MEMORY_SCOPE_AGENT) < NBLK)
        __builtin_amdgcn_s_sleep(1);
    }
    __syncthreads();

    // ---- phase C: c-BN + h writes into LDS tiles ----
    if (runL0) {
      float S, Q; ld_sq(&stp[3072 + u * 2], S, Q);
      float m_ = S * (1.f / BB), v_ = Q * (1.f / BB) - m_ * m_;
      float ac = p_gc0 * rsqrtf(v_ + EPSB), dc = p_bc0 - ac * m_;
#pragma unroll
      for (int mt = 0; mt < 2; ++mt)
#pragma unroll
        for (int r = 0; r < 4; ++r)
          h0t[mt * 16 + lq * 4 + r][u] = f2bf(so0[mt][r] * tanhf_(ac * c0st[mt][r] + dc));
    }
    if (runL1) {
      float S, Q; ld_sq(&stp[3072 + 256 + u * 2], S, Q);
      float m_ = S * (1.f / BB), v_ = Q * (1.f / BB) - m_ * m_;
      float ac = p_gc1 * rsqrtf(v_ + EPSB), dc = p_bc1 - ac * m_;
#pragma unroll
      for (int mt = 0; mt < 2; ++mt)
#pragma unroll
        for (int r = 0; r < 4; ++r)
          h1t[mt * 16 + lq * 4 + r][u] = f2bf(so1[mt][r] * tanhf_(ac * c1st[mt][r] + dc));
    }
    // zero this parity's stats slice (next used at s+2; 2 barriers in between)
    if (tid < 112) szero(&g_stats[p][nb * 112 + tid]);
    __syncthreads();   // h tiles visible block-wide for next step
  }

  // h1t now holds h1(TT-1): write this block's 32 rows
  {
    int idx = tid * 8;                 // 512*8 = 4096 = 32*128
    int row = idx >> 7, colk = idx & 127;
    uint4 v = *reinterpret_cast<uint4*>(&h1t[row][colk]);
    *reinterpret_cast<uint4*>(g_hlast + (size_t)(row0 + row) * HH + colk) = v;
  }
}

// ---- epilogue: emb = h_last @ fc_w + fc_b (bf16 out) ----
__global__ __launch_bounds__(256) void kfc(const float* __restrict__ fcb) {
  const int tid = threadIdx.x, w = tid >> 6, l = tid & 63;
  const int lm = l & 15, lq = l >> 4;
  const int col = blockIdx.x * 16 + lm;   // grid 16
  v8s bf[4];
#pragma unroll
  for (int ks = 0; ks < 4; ++ks) bf[ks] = ld8(&g_fcwt[col * HH + ks * 32 + lq * 8]);
  const float bias = fcb[col];
  const v4f vz = {0.f, 0.f, 0.f, 0.f};
#pragma unroll
  for (int mt = 0; mt < 16; ++mt) {
    const int rowa = w * 256 + mt * 16 + lm;
    const ush* ap = g_hlast + (size_t)rowa * HH + lq * 8;
    v4f acc = vz;
#pragma unroll
    for (int ks = 0; ks < 4; ++ks)
      acc = __builtin_amdgcn_mfma_f32_16x16x32_bf16(ld8(ap + ks * 32), bf[ks], acc, 0, 0, 0);
#pragma unroll
    for (int r = 0; r < 4; ++r) {
      int row = w * 256 + mt * 16 + lq * 4 + r;
      g_emb[row * OUTN + col] = f2bf(acc[r] + bias);
    }
  }
}

// ---- epilogue: out = emb @ dec_w + dec_b (fp32 out) ----
__global__ __launch_bounds__(256) void kdec(const float* __restrict__ decb, float* __restrict__ out) {
  const int tid = threadIdx.x, w = tid >> 6, l = tid & 63;
  const int lm = l & 15, lq = l >> 4;
  const int col = blockIdx.x * 16 + lm;   // grid 600
  v8s bf[8];
#pragma unroll
  for (int ks = 0; ks < 8; ++ks) bf[ks] = ld8(&g_decwt[(size_t)col * OUTN + ks * 32 + lq * 8]);
  const float bias = decb[col];
  const v4f vz = {0.f, 0.f, 0.f, 0.f};
#pragma unroll
  for (int mt = 0; mt < 16; ++mt) {
    const int rowa = w * 256 + mt * 16 + lm;
    const ush* ap = g_emb + (size_t)rowa * OUTN + lq * 8;
    v4f acc = vz;
#pragma unroll
    for (int ks = 0; ks < 8; ++ks)
      acc = __builtin_amdgcn_mfma_f32_16x16x32_bf16(ld8(ap + ks * 32), bf[ks], acc, 0, 0, 0);
#pragma unroll
    for (int r = 0; r < 4; ++r) {
      int row = w * 256 + mt * 16 + lq * 4 + r;
      out[(size_t)row * DECN + col] = acc[r] + bias;
    }
  }
}

extern "C" void kernel_launch(void* const* d_in, const int* in_sizes, int n_in,
                              void* d_out, int out_size, void* d_ws, size_t ws_size,
                              hipStream_t stream) {
  const float* seq  = (const float*)d_in[0];
  const float* Wih0 = (const float*)d_in[1];
  const float* Whh0 = (const float*)d_in[2];
  const float* b0   = (const float*)d_in[3];
  const float* gih0 = (const float*)d_in[4];
  const float* bih0 = (const float*)d_in[5];
  const float* ghh0 = (const float*)d_in[6];
  const float* bhh0 = (const float*)d_in[7];
  const float* gc0  = (const float*)d_in[8];
  const float* bc0  = (const float*)d_in[9];
  const float* Wih1 = (const float*)d_in[10];
  const float* Whh1 = (const float*)d_in[11];
  const float* b1   = (const float*)d_in[12];
  const float* gih1 = (const float*)d_in[13];
  const float* bih1 = (const float*)d_in[14];
  const float* ghh1 = (const float*)d_in[15];
  const float* bhh1 = (const float*)d_in[16];
  const float* gc1  = (const float*)d_in[17];
  const float* bc1  = (const float*)d_in[18];
  const float* fcw  = (const float*)d_in[19];
  const float* fcb  = (const float*)d_in[20];
  const float* decw = (const float*)d_in[21];
  const float* decb = (const float*)d_in[22];
  float* out = (float*)d_out;
  (void)in_sizes; (void)n_in; (void)out_size; (void)d_ws; (void)ws_size;

  kzero<<<dim3(32), dim3(256), 0, stream>>>();
  kpackx<<<dim3((TT * BB * KXP) / 256), dim3(256), 0, stream>>>(seq);
  kpackw<<<dim3(10688), dim3(256), 0, stream>>>(Wih0, Whh0, Wih1, Whh1, fcw, decw);
  kprep<<<dim3(TT * 32), dim3(256), 0, stream>>>(gih0, bih0, b0);
  krec5<<<dim3(NBLK), dim3(NTHR), 0, stream>>>(ghh0, bhh0, gc0, bc0,
                                               gih1, bih1, ghh1, bhh1, b1, gc1, bc1);
  kfc<<<dim3(16), dim3(256), 0, stream>>>(fcb);
  kdec<<<dim3(600), dim3(256), 0, stream>>>(decb, out);
}

// Round 6
// 5353.319 us; speedup vs baseline: 1.5864x; 1.0550x over previous
//
#include <hip/hip_runtime.h>
#include <stdint.h>
#include <stddef.h>

#define TT   128
#define BB   1024
#define INN  75
#define HH   128
#define KXP  96
#define OUTN 256
#define DECN 9600
#define NBLK 32
#define NTHR 512
#define EPSB 1e-5f

typedef short v8s __attribute__((ext_vector_type(8)));   // 8 bf16 (4 VGPR) MFMA frag
typedef float v4f __attribute__((ext_vector_type(4)));   // 4 fp32 acc frag
typedef unsigned short ush;
typedef unsigned int   u32;
typedef unsigned long long u64;

// ---- static device workspace (fully rewritten every launch) ----
__device__ __align__(256) ush g_xpad[(size_t)TT * BB * KXP];   // x padded to K=96, [t][b][k] bf16
__device__ __align__(256) u64 g_G1u[(size_t)TT * BB * 128];    // BN(x@Wih0)+b0, [t][row][512 bf16] as u64
__device__ __align__(256) u64 g_h0s[(size_t)TT * BB * 32];     // h0 stream [t][row][128 bf16] as u64
__device__ __align__(256) u64 g_h1s[(size_t)TT * BB * 32];     // h1 stream
// weights [m][k] bf16, m permuted: origcol(m) = (m&3)*128 + (m>>4)*4 + ((m>>2)&3)
__device__ __align__(256) ush g_wtih0[512 * KXP];
__device__ __align__(256) ush g_wthh0[512 * HH];
__device__ __align__(256) ush g_wtih1[512 * HH];
__device__ __align__(256) ush g_wthh1[512 * HH];
__device__ __align__(256) ush g_fcwt[OUTN * HH];               // fc_w^T [col][k]
__device__ __align__(256) ush g_decwt[(size_t)DECN * OUTN];    // dec_w^T [col][k]
__device__ __align__(256) ush g_emb[BB * OUTN];                // fc output bf16
__device__ __align__(256) u32 g_ctrS[TT + 4];                  // per-step barrier counters

// ---- helpers ----
__device__ __forceinline__ ush f2bf(float f) {
  u32 u = __float_as_uint(f);
  u32 r = (u + 0x7FFFu + ((u >> 16) & 1u)) >> 16;   // RNE
  return (ush)r;
}
__device__ __forceinline__ float bf2f(ush u) { return __uint_as_float(((u32)u) << 16); }
__device__ __forceinline__ float sigf(float x)  { return 1.f / (1.f + __expf(-x)); }
__device__ __forceinline__ float tanhf_(float x){ float e = __expf(2.f * x); return 1.f - 2.f / (e + 1.f); }
__device__ __forceinline__ v8s ld8(const ush* p) { return *reinterpret_cast<const v8s*>(p); }
__device__ __forceinline__ int origcol(int m) { return (m & 3) * 128 + (m >> 4) * 4 + ((m >> 2) & 3); }

// ---- prep kernels ----
__global__ void kzero() {
  int idx = threadIdx.x;            // 1 block x 256
  if (idx < TT + 4) g_ctrS[idx] = 0u;
}

__global__ void kpackx(const float* __restrict__ seq) {
  int idx = blockIdx.x * 256 + threadIdx.x;   // < TT*BB*KXP
  int kk = idx % KXP; int rest = idx / KXP;
  int b = rest % BB;  int t = rest / BB;
  float v = (kk < INN) ? seq[((size_t)b * TT + t) * INN + kk] : 0.f;
  g_xpad[idx] = f2bf(v);
}

__global__ void kpackw(const float* __restrict__ Wih0, const float* __restrict__ Whh0,
                       const float* __restrict__ Wih1, const float* __restrict__ Whh1,
                       const float* __restrict__ fcw,  const float* __restrict__ decw) {
  int idx = blockIdx.x * 256 + threadIdx.x;   // grid 10688
  if (idx < 49152) {                          // wtih0: [m][96]
    int m = idx / KXP, k = idx % KXP;
    g_wtih0[idx] = f2bf((k < INN) ? Wih0[k * 512 + origcol(m)] : 0.f);
  } else if (idx < 114688) {
    int j = idx - 49152; int m = j / HH, k = j % HH;
    g_wthh0[j] = f2bf(Whh0[k * 512 + origcol(m)]);
  } else if (idx < 180224) {
    int j = idx - 114688; int m = j / HH, k = j % HH;
    g_wtih1[j] = f2bf(Wih1[k * 512 + origcol(m)]);
  } else if (idx < 245760) {
    int j = idx - 180224; int m = j / HH, k = j % HH;
    g_wthh1[j] = f2bf(Whh1[k * 512 + origcol(m)]);
  } else if (idx < 278528) {                  // fcwt [c][128]
    int j = idx - 245760; int c = j / HH, k = j % HH;
    g_fcwt[j] = f2bf(fcw[k * OUTN + c]);
  } else {                                    // decwt [c][256], coalesced reads
    int j = idx - 278528; int n = j % DECN, k = j / DECN;
    g_decwt[(size_t)n * OUTN + k] = f2bf(decw[(size_t)k * DECN + n]);
  }
}

// G1u[t][row][m] = BN_ih0(x_t @ Wih0)[origcol(m)] + b0, transposed-MFMA orientation.
// grid TT*8 (t, ct): block covers 64 m-cols (4 tiles), 8 waves split the 1024 rows.
__global__ __launch_bounds__(NTHR) void kprep(const float* __restrict__ gih0,
                                              const float* __restrict__ bih0,
                                              const float* __restrict__ b0) {
  const int t = blockIdx.x >> 3, ct = blockIdx.x & 7;
  const int tid = threadIdx.x, wv = tid >> 6, l = tid & 63;
  const int lm = l & 15, lq = l >> 4;
  const int R0 = wv * 128;
  __shared__ float sred[8][64][2];
  __shared__ float scoef[64][2];

  v8s af[4][3];
#pragma unroll
  for (int tt = 0; tt < 4; ++tt)
#pragma unroll
    for (int ks = 0; ks < 3; ++ks)
      af[tt][ks] = ld8(&g_wtih0[(ct * 64 + tt * 16 + lm) * KXP + ks * 32 + lq * 8]);

  const v4f vz = {0.f, 0.f, 0.f, 0.f};
  v4f acc[8][4];
#pragma unroll
  for (int mt = 0; mt < 8; ++mt)
#pragma unroll
    for (int tt = 0; tt < 4; ++tt) acc[mt][tt] = vz;

#pragma unroll
  for (int mt = 0; mt < 8; ++mt) {
    const ush* xr = g_xpad + ((size_t)t * BB + R0 + mt * 16 + lm) * KXP + lq * 8;
    v8s bx0 = ld8(xr), bx1 = ld8(xr + 32), bx2 = ld8(xr + 64);
#pragma unroll
    for (int tt = 0; tt < 4; ++tt) {
      acc[mt][tt] = __builtin_amdgcn_mfma_f32_16x16x32_bf16(af[tt][0], bx0, acc[mt][tt], 0, 0, 0);
      acc[mt][tt] = __builtin_amdgcn_mfma_f32_16x16x32_bf16(af[tt][1], bx1, acc[mt][tt], 0, 0, 0);
      acc[mt][tt] = __builtin_amdgcn_mfma_f32_16x16x32_bf16(af[tt][2], bx2, acc[mt][tt], 0, 0, 0);
    }
  }
  // stats per m-col (lane holds cols tt*16+lq*4+r, rows lm over 8 mt)
  float S[4][4], Q[4][4];
#pragma unroll
  for (int tt = 0; tt < 4; ++tt)
#pragma unroll
    for (int r = 0; r < 4; ++r) {
      float s = 0.f, q = 0.f;
#pragma unroll
      for (int mt = 0; mt < 8; ++mt) { float a = acc[mt][tt][r]; s += a; q += a * a; }
#pragma unroll
      for (int off = 1; off < 16; off <<= 1) { s += __shfl_xor(s, off); q += __shfl_xor(q, off); }
      S[tt][r] = s; Q[tt][r] = q;
    }
  if (lm == 0)
#pragma unroll
    for (int tt = 0; tt < 4; ++tt)
#pragma unroll
      for (int r = 0; r < 4; ++r) {
        sred[wv][tt * 16 + lq * 4 + r][0] = S[tt][r];
        sred[wv][tt * 16 + lq * 4 + r][1] = Q[tt][r];
      }
  __syncthreads();
  if (tid < 64) {
    float Sa = 0.f, Qa = 0.f;
#pragma unroll
    for (int w8 = 0; w8 < 8; ++w8) { Sa += sred[w8][tid][0]; Qa += sred[w8][tid][1]; }
    int oc = origcol(ct * 64 + tid);
    float m_ = Sa * (1.f / BB), v_ = Qa * (1.f / BB) - m_ * m_;
    float A = gih0[oc] * rsqrtf(v_ + EPSB);
    scoef[tid][0] = A; scoef[tid][1] = bih0[oc] - A * m_ + b0[oc];
  }
  __syncthreads();
  float CA[4][4], CD[4][4];
#pragma unroll
  for (int tt = 0; tt < 4; ++tt)
#pragma unroll
    for (int r = 0; r < 4; ++r) {
      CA[tt][r] = scoef[tt * 16 + lq * 4 + r][0];
      CD[tt][r] = scoef[tt * 16 + lq * 4 + r][1];
    }
#pragma unroll
  for (int mt = 0; mt < 8; ++mt) {
    const size_t rowbase = ((size_t)t * BB + R0 + mt * 16 + lm) * 128;
#pragma unroll
    for (int tt = 0; tt < 4; ++tt) {
      u32 lo = (u32)f2bf(CA[tt][0] * acc[mt][tt][0] + CD[tt][0])
             | ((u32)f2bf(CA[tt][1] * acc[mt][tt][1] + CD[tt][1]) << 16);
      u32 hi = (u32)f2bf(CA[tt][2] * acc[mt][tt][2] + CD[tt][2])
             | ((u32)f2bf(CA[tt][3] * acc[mt][tt][3] + CD[tt][3]) << 16);
      g_G1u[rowbase + ct * 16 + tt * 4 + lq] = (u64)lo | ((u64)hi << 32);
    }
  }
}

// ---- fused persistent recurrent kernel: 32 blocks x 512 thr (8 waves).
// Column partition: block owns 4 units (16 gate cols, gate-minor) for BOTH layers.
// Transposed MFMA (A=W^T, B=h^T): lane holds row=lm, unit=lq, 4 gates in regs ->
// in-register pointwise, block-local BN stats, ONE grid barrier per step.
__global__ __launch_bounds__(NTHR, 1) void krec6(
    const float* __restrict__ ghh0, const float* __restrict__ bhh0,
    const float* __restrict__ gc0,  const float* __restrict__ bc0,
    const float* __restrict__ gih1, const float* __restrict__ bih1,
    const float* __restrict__ ghh1, const float* __restrict__ bhh1,
    const float* __restrict__ b1,   const float* __restrict__ gc1,
    const float* __restrict__ bc1) {
  const int tid = threadIdx.x;
  const int wv = tid >> 6, l = tid & 63;
  const int lm = l & 15, lq = l >> 4;
  const int nb = blockIdx.x;
  const int R0 = wv * 128;

  __shared__ float sparam[16][7];
  __shared__ float scparam[4][4];
  __shared__ float sred[8][16][6];
  __shared__ float scoef[16][5];
  __shared__ float scred[8][4][4];
  __shared__ float sccoef[4][4];

  if (tid < 16) {
    int oc = origcol(nb * 16 + tid);
    sparam[tid][0] = ghh0[oc]; sparam[tid][1] = bhh0[oc];
    sparam[tid][2] = gih1[oc]; sparam[tid][3] = bih1[oc];
    sparam[tid][4] = ghh1[oc]; sparam[tid][5] = bhh1[oc];
    sparam[tid][6] = b1[oc];
  }
  if (tid >= 16 && tid < 20) {
    int u = nb * 4 + (tid - 16);
    scparam[tid - 16][0] = gc0[u]; scparam[tid - 16][1] = bc0[u];
    scparam[tid - 16][2] = gc1[u]; scparam[tid - 16][3] = bc1[u];
  }
  __syncthreads();

  const ush* const h0r = reinterpret_cast<const ush*>(g_h0s);
  const ush* const h1r = reinterpret_cast<const ush*>(g_h1s);

  float c0st[8], c1st[8], so0[8], so1[8];
#pragma unroll
  for (int i = 0; i < 8; ++i) { c0st[i] = 0.f; c1st[i] = 0.f; so0[i] = 0.f; so1[i] = 0.f; }

  const v4f vz = {0.f, 0.f, 0.f, 0.f};

  for (int s = 0; s <= TT; ++s) {
    const bool aL0 = (s < TT), aL1 = (s >= 1), ah0 = (s >= 1), ah1 = (s >= 2);

    // weight A-frags (L2-hot, reloaded per step to cap registers)
    v8s af0[4], af1[4], af2[4];
#pragma unroll
    for (int ks = 0; ks < 4; ++ks) {
      af0[ks] = ld8(&g_wthh0[(nb * 16 + lm) * HH + ks * 32 + lq * 8]);
      af1[ks] = ld8(&g_wtih1[(nb * 16 + lm) * HH + ks * 32 + lq * 8]);
      af2[ks] = ld8(&g_wthh1[(nb * 16 + lm) * HH + ks * 32 + lq * 8]);
    }
    // G1 loads (this lane's 4 gate cols, its rows)
    u64 gl[8];
    if (aL0) {
#pragma unroll
      for (int mt = 0; mt < 8; ++mt)
        gl[mt] = g_G1u[((size_t)s * BB + R0 + mt * 16 + lm) * 128 + nb * 4 + lq];
    }

    v4f P0[8], P1[8], P2[8];
#pragma unroll
    for (int mt = 0; mt < 8; ++mt) { P0[mt] = vz; P1[mt] = vz; P2[mt] = vz; }

    if (ah0) {
#pragma unroll
      for (int mt = 0; mt < 8; ++mt) {
        const ush* hp = h0r + ((size_t)(s - 1) * BB + R0 + mt * 16 + lm) * HH + lq * 8;
#pragma unroll
        for (int ks = 0; ks < 4; ++ks) {
          v8s b = ld8(hp + ks * 32);
          P0[mt] = __builtin_amdgcn_mfma_f32_16x16x32_bf16(af0[ks], b, P0[mt], 0, 0, 0);
          P1[mt] = __builtin_amdgcn_mfma_f32_16x16x32_bf16(af1[ks], b, P1[mt], 0, 0, 0);
        }
      }
    }
    if (ah1) {
#pragma unroll
      for (int mt = 0; mt < 8; ++mt) {
        const ush* hp = h1r + ((size_t)(s - 2) * BB + R0 + mt * 16 + lm) * HH + lq * 8;
#pragma unroll
        for (int ks = 0; ks < 4; ++ks) {
          v8s b = ld8(hp + ks * 32);
          P2[mt] = __builtin_amdgcn_mfma_f32_16x16x32_bf16(af2[ks], b, P2[mt], 0, 0, 0);
        }
      }
    }

    // ---- gate stats (block-local): per col S,Q over rows ----
    float S[3][4], Q[3][4];
#pragma unroll
    for (int st = 0; st < 3; ++st)
#pragma unroll
      for (int r = 0; r < 4; ++r) { S[st][r] = 0.f; Q[st][r] = 0.f; }
#pragma unroll
    for (int mt = 0; mt < 8; ++mt)
#pragma unroll
      for (int r = 0; r < 4; ++r) {
        float a = P0[mt][r]; S[0][r] += a; Q[0][r] += a * a;
        float b = P1[mt][r]; S[1][r] += b; Q[1][r] += b * b;
        float c = P2[mt][r]; S[2][r] += c; Q[2][r] += c * c;
      }
#pragma unroll
    for (int st = 0; st < 3; ++st)
#pragma unroll
      for (int r = 0; r < 4; ++r) {
        float s_ = S[st][r], q_ = Q[st][r];
#pragma unroll
        for (int off = 1; off < 16; off <<= 1) { s_ += __shfl_xor(s_, off); q_ += __shfl_xor(q_, off); }
        S[st][r] = s_; Q[st][r] = q_;
      }
    if (lm == 0)
#pragma unroll
      for (int r = 0; r < 4; ++r) {
        sred[wv][lq * 4 + r][0] = S[0][r]; sred[wv][lq * 4 + r][1] = Q[0][r];
        sred[wv][lq * 4 + r][2] = S[1][r]; sred[wv][lq * 4 + r][3] = Q[1][r];
        sred[wv][lq * 4 + r][4] = S[2][r]; sred[wv][lq * 4 + r][5] = Q[2][r];
      }
    __syncthreads();
    if (tid < 16) {
      float t6[6] = {0.f, 0.f, 0.f, 0.f, 0.f, 0.f};
#pragma unroll
      for (int w8 = 0; w8 < 8; ++w8)
#pragma unroll
        for (int j = 0; j < 6; ++j) t6[j] += sred[w8][tid][j];
      float m0 = t6[0] * (1.f / BB), v0 = t6[1] * (1.f / BB) - m0 * m0;
      float A0v = sparam[tid][0] * rsqrtf(v0 + EPSB);
      float D0v = sparam[tid][1] - A0v * m0;
      float m1 = t6[2] * (1.f / BB), v1 = t6[3] * (1.f / BB) - m1 * m1;
      float Aiv = sparam[tid][2] * rsqrtf(v1 + EPSB);
      float m2 = t6[4] * (1.f / BB), v2 = t6[5] * (1.f / BB) - m2 * m2;
      float Ahv = sparam[tid][4] * rsqrtf(v2 + EPSB);
      float D1v = sparam[tid][3] - Aiv * m1 + sparam[tid][5] - Ahv * m2 + sparam[tid][6];
      scoef[tid][0] = A0v; scoef[tid][1] = D0v;
      scoef[tid][2] = Aiv; scoef[tid][3] = Ahv; scoef[tid][4] = D1v;
    }
    __syncthreads();
    float A0[4], D0[4], Ai[4], Ah[4], D1[4];
#pragma unroll
    for (int r = 0; r < 4; ++r) {
      A0[r] = scoef[lq * 4 + r][0]; D0[r] = scoef[lq * 4 + r][1];
      Ai[r] = scoef[lq * 4 + r][2]; Ah[r] = scoef[lq * 4 + r][3]; D1[r] = scoef[lq * 4 + r][4];
    }

    // ---- pointwise, fully in-register (regs r = gates f,i,o,g of unit lq) ----
    float cS0 = 0.f, cQ0 = 0.f, cS1 = 0.f, cQ1 = 0.f;
#pragma unroll
    for (int mt = 0; mt < 8; ++mt) {
      if (aL0) {
        u64 g = gl[mt];
        float gf = bf2f((ush)(g))       + A0[0] * P0[mt][0] + D0[0];
        float gi = bf2f((ush)(g >> 16)) + A0[1] * P0[mt][1] + D0[1];
        float go = bf2f((ush)(g >> 32)) + A0[2] * P0[mt][2] + D0[2];
        float gg = bf2f((ush)(g >> 48)) + A0[3] * P0[mt][3] + D0[3];
        float c1 = sigf(gf) * c0st[mt] + sigf(gi) * tanhf_(gg);
        c0st[mt] = c1; so0[mt] = sigf(go);
        cS0 += c1; cQ0 += c1 * c1;
      }
      if (aL1) {
        float gf = Ai[0] * P1[mt][0] + Ah[0] * P2[mt][0] + D1[0];
        float gi = Ai[1] * P1[mt][1] + Ah[1] * P2[mt][1] + D1[1];
        float go = Ai[2] * P1[mt][2] + Ah[2] * P2[mt][2] + D1[2];
        float gg = Ai[3] * P1[mt][3] + Ah[3] * P2[mt][3] + D1[3];
        float c1 = sigf(gf) * c1st[mt] + sigf(gi) * tanhf_(gg);
        c1st[mt] = c1; so1[mt] = sigf(go);
        cS1 += c1; cQ1 += c1 * c1;
      }
    }
    // ---- c-BN stats (block-local) ----
#pragma unroll
    for (int off = 1; off < 16; off <<= 1) {
      cS0 += __shfl_xor(cS0, off); cQ0 += __shfl_xor(cQ0, off);
      cS1 += __shfl_xor(cS1, off); cQ1 += __shfl_xor(cQ1, off);
    }
    if (lm == 0) {
      scred[wv][lq][0] = cS0; scred[wv][lq][1] = cQ0;
      scred[wv][lq][2] = cS1; scred[wv][lq][3] = cQ1;
    }
    __syncthreads();
    if (tid < 4) {
      float t4[4] = {0.f, 0.f, 0.f, 0.f};
#pragma unroll
      for (int w8 = 0; w8 < 8; ++w8)
#pragma unroll
        for (int j = 0; j < 4; ++j) t4[j] += scred[w8][tid][j];
      float m0 = t4[0] * (1.f / BB), v0 = t4[1] * (1.f / BB) - m0 * m0;
      float ac0 = scparam[tid][0] * rsqrtf(v0 + EPSB);
      float m1 = t4[2] * (1.f / BB), v1 = t4[3] * (1.f / BB) - m1 * m1;
      float ac1 = scparam[tid][2] * rsqrtf(v1 + EPSB);
      sccoef[tid][0] = ac0; sccoef[tid][1] = scparam[tid][1] - ac0 * m0;
      sccoef[tid][2] = ac1; sccoef[tid][3] = scparam[tid][3] - ac1 * m1;
    }
    __syncthreads();
    const float ac0 = sccoef[lq][0], dc0 = sccoef[lq][1];
    const float ac1 = sccoef[lq][2], dc1 = sccoef[lq][3];

    // ---- h outputs: pack 4 units via shfl, agent-atomic u64 store (LLC write-through) ----
    if (aL0) {
#pragma unroll
      for (int mt = 0; mt < 8; ++mt) {
        u32 v = (u32)f2bf(so0[mt] * tanhf_(ac0 * c0st[mt] + dc0));
        u32 a = v | (__shfl_xor(v, 16) << 16);   // valid on even lq
        u32 b = __shfl_xor(a, 32);               // lq0 <- (u2,u3)
        if (l < 16)
          __hip_atomic_store(&g_h0s[((size_t)s * BB + R0 + mt * 16 + lm) * 32 + nb],
                             (u64)a | ((u64)b << 32), __ATOMIC_RELAXED, __HIP_MEMORY_SCOPE_AGENT);
      }
    }
    if (aL1) {
#pragma unroll
      for (int mt = 0; mt < 8; ++mt) {
        u32 v = (u32)f2bf(so1[mt] * tanhf_(ac1 * c1st[mt] + dc1));
        u32 a = v | (__shfl_xor(v, 16) << 16);
        u32 b = __shfl_xor(a, 32);
        if (l < 16)
          __hip_atomic_store(&g_h1s[((size_t)(s - 1) * BB + R0 + mt * 16 + lm) * 32 + nb],
                             (u64)a | ((u64)b << 32), __ATOMIC_RELAXED, __HIP_MEMORY_SCOPE_AGENT);
      }
    }

    // ---- single grid barrier per step ----
    if (s < TT) {
      __builtin_amdgcn_s_waitcnt(0x0f70);   // vmcnt(0): h stores acked at LLC
      __syncthreads();
      if (tid == 0) {
        __hip_atomic_fetch_add(&g_ctrS[s], 1u, __ATOMIC_RELEASE, __HIP_MEMORY_SCOPE_AGENT);
        while (__hip_atomic_load(&g_ctrS[s], __ATOMIC_RELAXED, __HIP_MEMORY_SCOPE_AGENT) < NBLK)
          __builtin_amdgcn_s_sleep(1);
      }
      __syncthreads();
    }
  }
}

// ---- epilogue: emb = h1(T-1) @ fc_w + fc_b (bf16 out) ----
__global__ __launch_bounds__(256) void kfc(const float* __restrict__ fcb) {
  const int tid = threadIdx.x, w = tid >> 6, l = tid & 63;
  const int lm = l & 15, lq = l >> 4;
  const int col = blockIdx.x * 16 + lm;   // grid 16
  const ush* hsrc = reinterpret_cast<const ush*>(g_h1s) + (size_t)(TT - 1) * BB * HH;
  v8s bf[4];
#pragma unroll
  for (int ks = 0; ks < 4; ++ks) bf[ks] = ld8(&g_fcwt[col * HH + ks * 32 + lq * 8]);
  const float bias = fcb[col];
  const v4f vz = {0.f, 0.f, 0.f, 0.f};
#pragma unroll
  for (int mt = 0; mt < 16; ++mt) {
    const int rowa = w * 256 + mt * 16 + lm;
    const ush* ap = hsrc + (size_t)rowa * HH + lq * 8;
    v4f acc = vz;
#pragma unroll
    for (int ks = 0; ks < 4; ++ks)
      acc = __builtin_amdgcn_mfma_f32_16x16x32_bf16(ld8(ap + ks * 32), bf[ks], acc, 0, 0, 0);
#pragma unroll
    for (int r = 0; r < 4; ++r) {
      int row = w * 256 + mt * 16 + lq * 4 + r;
      g_emb[row * OUTN + col] = f2bf(acc[r] + bias);
    }
  }
}

// ---- epilogue: out = emb @ dec_w + dec_b (fp32 out) ----
__global__ __launch_bounds__(256) void kdec(const float* __restrict__ decb, float* __restrict__ out) {
  const int tid = threadIdx.x, w = tid >> 6, l = tid & 63;
  const int lm = l & 15, lq = l >> 4;
  const int col = blockIdx.x * 16 + lm;   // grid 600
  v8s bf[8];
#pragma unroll
  for (int ks = 0; ks < 8; ++ks) bf[ks] = ld8(&g_decwt[(size_t)col * OUTN + ks * 32 + lq * 8]);
  const float bias = decb[col];
  const v4f vz = {0.f, 0.f, 0.f, 0.f};
#pragma unroll
  for (int mt = 0; mt < 16; ++mt) {
    const int rowa = w * 256 + mt * 16 + lm;
    const ush* ap = g_emb + (size_t)rowa * OUTN + lq * 8;
    v4f acc = vz;
#pragma unroll
    for (int ks = 0; ks < 8; ++ks)
      acc = __builtin_amdgcn_mfma_f32_16x16x32_bf16(ld8(ap + ks * 32), bf[ks], acc, 0, 0, 0);
#pragma unroll
    for (int r = 0; r < 4; ++r) {
      int row = w * 256 + mt * 16 + lq * 4 + r;
      out[(size_t)row * DECN + col] = acc[r] + bias;
    }
  }
}

extern "C" void kernel_launch(void* const* d_in, const int* in_sizes, int n_in,
                              void* d_out, int out_size, void* d_ws, size_t ws_size,
                              hipStream_t stream) {
  const float* seq  = (const float*)d_in[0];
  const float* Wih0 = (const float*)d_in[1];
  const float* Whh0 = (const float*)d_in[2];
  const float* b0   = (const float*)d_in[3];
  const float* gih0 = (const float*)d_in[4];
  const float* bih0 = (const float*)d_in[5];
  const float* ghh0 = (const float*)d_in[6];
  const float* bhh0 = (const float*)d_in[7];
  const float* gc0  = (const float*)d_in[8];
  const float* bc0  = (const float*)d_in[9];
  const float* Wih1 = (const float*)d_in[10];
  const float* Whh1 = (const float*)d_in[11];
  const float* b1   = (const float*)d_in[12];
  const float* gih1 = (const float*)d_in[13];
  const float* bih1 = (const float*)d_in[14];
  const float* ghh1 = (const float*)d_in[15];
  const float* bhh1 = (const float*)d_in[16];
  const float* gc1  = (const float*)d_in[17];
  const float* bc1  = (const float*)d_in[18];
  const float* fcw  = (const float*)d_in[19];
  const float* fcb  = (const float*)d_in[20];
  const float* decw = (const float*)d_in[21];
  const float* decb = (const float*)d_in[22];
  float* out = (float*)d_out;
  (void)in_sizes; (void)n_in; (void)out_size; (void)d_ws; (void)ws_size;

  kzero<<<dim3(1), dim3(256), 0, stream>>>();
  kpackx<<<dim3((TT * BB * KXP) / 256), dim3(256), 0, stream>>>(seq);
  kpackw<<<dim3(10688), dim3(256), 0, stream>>>(Wih0, Whh0, Wih1, Whh1, fcw, decw);
  kprep<<<dim3(TT * 8), dim3(NTHR), 0, stream>>>(gih0, bih0, b0);
  krec6<<<dim3(NBLK), dim3(NTHR), 0, stream>>>(ghh0, bhh0, gc0, bc0,
                                               gih1, bih1, ghh1, bhh1, b1, gc1, bc1);
  kfc<<<dim3(16), dim3(256), 0, stream>>>(fcb);
  kdec<<<dim3(600), dim3(256), 0, stream>>>(decb, out);
}